// Round 3
// baseline (1267.308 us; speedup 1.0000x reference)
//
#include <hip/hip_runtime.h>
#include <hip/hip_fp16.h>

#define TOTAL 131072
#define SEGN  256
#define FEAT  78
#define FPAD  96
#define HID   1024
#define NCLS  10
#define FCHUNK 32

typedef __attribute__((ext_vector_type(8))) short short8;
typedef __attribute__((ext_vector_type(4))) float floatx4;

typedef __attribute__((address_space(1))) void gvoid_t;
typedef __attribute__((address_space(3))) void svoid_t;

__device__ __forceinline__ void async_copy16(const void* gsrc, void* ldst) {
    __builtin_amdgcn_global_load_lds((gvoid_t*)(void*)gsrc, (svoid_t*)ldst, 16, 0, 0);
}

// ---------------- conversion kernels ----------------

__global__ void conv_x_slab(const float* __restrict__ x, __half* __restrict__ xb,
                            int row0, int rows) {
    int idx = blockIdx.x * 256 + threadIdx.x;
    if (idx >= rows * FPAD) return;
    int col = idx % FPAD;
    int r   = idx / FPAD;
    float v = (col < FEAT) ? x[(size_t)(row0 + r) * FEAT + col] : 0.0f;
    xb[idx] = __float2half(v);
}

__global__ void conv_wt_kernel(const float* __restrict__ W, __half* __restrict__ Wt,
                               int K, int N, int Kpad) {
    int idx = blockIdx.x * 256 + threadIdx.x;
    if (idx >= N * Kpad) return;
    int k = idx % Kpad;
    int n = idx / Kpad;
    float v = (k < K) ? W[(size_t)k * N + n] : 0.0f;
    Wt[idx] = __float2half(v);
}

__global__ void conv_w4_kernel(const float* __restrict__ W2, const float* __restrict__ W3,
                               const float* __restrict__ W4, const float* __restrict__ W6,
                               __half* __restrict__ w2t, __half* __restrict__ w3t,
                               __half* __restrict__ w4t, __half* __restrict__ w6t) {
    int idx = blockIdx.x * 256 + threadIdx.x;
    if (idx >= HID * HID) return;
    int k = idx % HID;
    int n = idx / HID;
    const float* Ws[4] = {W2, W3, W4, W6};
    __half* Ts[4] = {w2t, w3t, w4t, w6t};
    int w = blockIdx.y;
    Ts[w][idx] = __float2half(Ws[w][(size_t)k * HID + n]);
}

// ---------------- 256x256 GEMM, m201-template 4-phase sub-tiles -------------
// C = act(A @ Bt^T + bias), A[M][K], Bt[N][K] f16, M%256==0, N%256==0, K%32==0,
// K/32 >= 4. 512 threads = 8 waves (2M x 4N), per-wave 128x64 output.
// K-sub-tiles of 32, 4-deep LDS ring (4 x 32KB), staging distance 3.
// Each sub-tile = 4 phases (C-quadrant granularity): per phase
//   { ds_read subtile (<=6 x b128) | stage 1/4 of tile T+3 | SBAR |
//     lgkmcnt(0)+sched_barrier | setprio(1) 8xMFMA setprio(0) | SBAR }
// vmcnt(8) ONCE per sub-tile (2 staged tiles stay in flight; never drained
// in the main loop). Tail drains 4 -> 0.
// LDS slot swizzle: slot ^= (row>>1)&3 applied as inverse perm on the GLOBAL
// source address (global_load_lds writes linearly) + same swizzle on ds_read.
// Optional fused score partials for layer 4: scores_p[bn*M + row].

#define VMCNT(n)  asm volatile("s_waitcnt vmcnt(" #n ")" ::: "memory")
#define LGKM0     do { asm volatile("s_waitcnt lgkmcnt(0)" ::: "memory"); \
                       __builtin_amdgcn_sched_barrier(0); } while (0)
#define SBAR      __builtin_amdgcn_s_barrier()

#define STAGE_A1(TT) async_copy16(gA + (TT)*32,            smem + (((TT)&3)<<14) + t*8)
#define STAGE_A2(TT) async_copy16(gA + (TT)*32 + kstr128,  smem + (((TT)&3)<<14) + 4096 + t*8)
#define STAGE_B1(TT) async_copy16(gB + (TT)*32,            smem + (((TT)&3)<<14) + 8192 + t*8)
#define STAGE_B2(TT) async_copy16(gB + (TT)*32 + kstr128,  smem + (((TT)&3)<<14) + 12288 + t*8)

#define MFMA8(AF, BF, MO, NO) \
    _Pragma("unroll") \
    for (int mi_ = 0; mi_ < 4; ++mi_) \
        _Pragma("unroll") \
        for (int ni_ = 0; ni_ < 2; ++ni_) \
            acc[(MO) + mi_][(NO) + ni_] = __builtin_amdgcn_mfma_f32_16x16x32_f16( \
                AF[mi_], BF[ni_], acc[(MO) + mi_][(NO) + ni_], 0, 0, 0)

#define SUBTILE(TT, STG, VM) do { \
    const short* base_ = smem + (((TT)&3)<<14); \
    short8 af_[4], ag_[4], bfA_[2], bfB_[2]; \
    /* ---- phase 0: Q00 ---- */ \
    _Pragma("unroll") \
    for (int i_ = 0; i_ < 4; ++i_) af_[i_]  = *(const short8*)&base_[aoff + i_*512]; \
    _Pragma("unroll") \
    for (int i_ = 0; i_ < 2; ++i_) bfA_[i_] = *(const short8*)&base_[8192 + boff + i_*512]; \
    if (STG) STAGE_A1((TT)+3); \
    SBAR; LGKM0; \
    __builtin_amdgcn_s_setprio(1); MFMA8(af_, bfA_, 0, 0); __builtin_amdgcn_s_setprio(0); \
    SBAR; \
    /* ---- phase 1: Q01 ---- */ \
    _Pragma("unroll") \
    for (int i_ = 0; i_ < 2; ++i_) bfB_[i_] = *(const short8*)&base_[8192 + boff + (2+i_)*512]; \
    if (STG) STAGE_A2((TT)+3); \
    SBAR; LGKM0; \
    __builtin_amdgcn_s_setprio(1); MFMA8(af_, bfB_, 0, 2); __builtin_amdgcn_s_setprio(0); \
    SBAR; \
    /* ---- phase 2: Q10 ---- */ \
    _Pragma("unroll") \
    for (int i_ = 0; i_ < 4; ++i_) ag_[i_] = *(const short8*)&base_[2048 + aoff + i_*512]; \
    if (STG) STAGE_B1((TT)+3); \
    SBAR; LGKM0; \
    __builtin_amdgcn_s_setprio(1); MFMA8(ag_, bfA_, 4, 0); __builtin_amdgcn_s_setprio(0); \
    SBAR; \
    /* ---- phase 3: Q11 (no reads) ---- */ \
    if (STG) STAGE_B2((TT)+3); \
    SBAR; \
    __builtin_amdgcn_s_setprio(1); MFMA8(ag_, bfB_, 4, 2); __builtin_amdgcn_s_setprio(0); \
    VM; \
    SBAR; \
} while (0)

__global__ __launch_bounds__(512, 2)
void gemm256(const __half* __restrict__ A, const __half* __restrict__ Bt,
             __half* __restrict__ C, const float* __restrict__ bias,
             int M, int N, int K, int relu_flag,
             const float* __restrict__ W5g, float* __restrict__ scores_p)
{
    __shared__ __align__(16) short smem[4 * 16384];   // 128 KB: 4 x (A 16KB + B 16KB)

    const int t   = threadIdx.x;
    const int nbn = N >> 8;
    const int nbm = M >> 8;
    int bm, bn;
    {
        const int b = blockIdx.x;
        if ((nbm & 7) == 0) {
            const int xcd = b & 7;
            const int j   = b >> 3;
            bm = xcd * (nbm >> 3) + j / nbn;
            bn = j % nbn;
        } else {
            bn = b % nbn;
            bm = b / nbn;
        }
    }
    const size_t m0 = (size_t)bm << 8;
    const size_t n0 = (size_t)bn << 8;
    const int wave = t >> 6, lane = t & 63;
    const int wmb = (wave >> 2) << 7;        // 0 / 128
    const int wnb = (wave & 3) << 6;         // 0 / 64 / 128 / 192
    const int l16 = lane & 15, q = lane >> 4;
    const int qa  = q ^ ((l16 >> 1) & 3);    // swizzled k-slot (read side)
    const int aoff = (wmb + l16) * 32 + qa * 8;
    const int boff = (wnb + l16) * 32 + qa * 8;

    // staging: linear LDS slot p = load*512 + t; row = p>>2;
    // source k-slot = (p&3) ^ ((p>>3)&3)  (inverse of read swizzle)
    const int rr = t >> 2;
    const int qs = ((t & 3) ^ ((t >> 3) & 3)) * 8;
    const __half* gA = A  + (m0 + rr) * K + qs;
    const __half* gB = Bt + (n0 + rr) * K + qs;
    const int kstr128 = K << 7;              // +128 rows

    floatx4 acc[8][4] = {};
    const int NT = K >> 5;

    // prologue: tiles 0,1,2 staged (12 loads); wait tile 0 (8 stay in flight)
    STAGE_A1(0); STAGE_A2(0); STAGE_B1(0); STAGE_B2(0);
    STAGE_A1(1); STAGE_A2(1); STAGE_B1(1); STAGE_B2(1);
    STAGE_A1(2); STAGE_A2(2); STAGE_B1(2); STAGE_B2(2);
    VMCNT(8);
    SBAR;

    int T = 0;
    for (; T < NT - 3; ++T)
        SUBTILE(T, 1, VMCNT(8));
    SUBTILE(T, 0, VMCNT(4)); ++T;
    SUBTILE(T, 0, VMCNT(0)); ++T;
    SUBTILE(T, 0, (void)0);
    __syncthreads();

    // ---- epilogue: full 256x256 tile through LDS, 16B coalesced stores ----
    __half* ct = (__half*)smem;
#pragma unroll
    for (int ni = 0; ni < 4; ++ni) {
        const int col = wnb + ni * 16 + l16;
        const float bv = bias[n0 + col];
#pragma unroll
        for (int mi = 0; mi < 8; ++mi) {
            const int r0l = wmb + mi * 16 + q * 4;
#pragma unroll
            for (int r = 0; r < 4; ++r) {
                float v = acc[mi][ni][r] + bv;
                if (relu_flag) v = fmaxf(v, 0.0f);
                ct[(r0l + r) * 256 + col] = __float2half(v);
            }
        }
    }
    __syncthreads();
#pragma unroll
    for (int it = 0; it < 16; ++it) {
        const int chunk = it * 512 + t;
        const int row = chunk >> 5;
        const int c32 = chunk & 31;
        short8 v = *(const short8*)&ct[row * 256 + c32 * 8];
        *(short8*)&C[(m0 + row) * N + n0 + c32 * 8] = v;
        if (scores_p) {
            const float* wv = W5g + n0 + c32 * 8;
            float p = 0.f;
#pragma unroll
            for (int j = 0; j < 8; ++j)
                p += __half2float(((const __half*)&v)[j]) * wv[j];
#pragma unroll
            for (int o = 16; o > 0; o >>= 1) p += __shfl_down(p, o, 32);
            if ((t & 31) == 0)
                scores_p[(size_t)bn * M + m0 + row] = p;
        }
    }
}

// ---------------- old 128x128 GEMM (kept for the small head GEMM) ----------

__global__ __launch_bounds__(256, 2)
void gemm_f16(const __half* __restrict__ A, const __half* __restrict__ Bt,
              __half* __restrict__ C, const float* __restrict__ bias,
              int M, int N, int K, int relu_flag,
              const float* __restrict__ W5g, float* __restrict__ scores_p)
{
    __shared__ __align__(16) short smem[4 * 128 * 32];
    short* lds_a0 = smem;
    short* lds_a1 = smem + 128 * 32;
    short* lds_b0 = smem + 2 * 128 * 32;
    short* lds_b1 = smem + 3 * 128 * 32;

    const int t   = threadIdx.x;
    const int nbn = N >> 7;
    const int nbm = M >> 7;
    int bm, bn;
    {
        const int b = blockIdx.x;
        if ((nbm & 7) == 0) {
            const int xcd = b & 7;
            const int j   = b >> 3;
            bm = xcd * (nbm >> 3) + j / nbn;
            bn = j % nbn;
        } else {
            bn = b % nbn;
            bm = b / nbn;
        }
    }
    const size_t m0 = (size_t)bm * 128;
    const size_t n0 = (size_t)bn * 128;
    const int wave = t >> 6, lane = t & 63;
    const int wm = (wave >> 1) << 6;
    const int wn = (wave & 1) << 6;
    const int l16 = lane & 15, q = lane >> 4;

    floatx4 acc[4][4] = {};

    const int c0 = t, c1 = t + 256;
    const __half* a0 = A  + (m0 + (size_t)(c0 >> 2)) * K + (c0 & 3) * 8;
    const __half* a1 = A  + (m0 + (size_t)(c1 >> 2)) * K + (c1 & 3) * 8;
    const __half* b0 = Bt + (n0 + (size_t)(c0 >> 2)) * K + (c0 & 3) * 8;
    const __half* b1 = Bt + (n0 + (size_t)(c1 >> 2)) * K + (c1 & 3) * 8;
    short* lA0_0 = &lds_a0[c0 * 8];
    short* lA0_1 = &lds_a0[c1 * 8];
    short* lA1_0 = &lds_a1[c0 * 8];
    short* lA1_1 = &lds_a1[c1 * 8];
    short* lB0_0 = &lds_b0[c0 * 8];
    short* lB0_1 = &lds_b0[c1 * 8];
    short* lB1_0 = &lds_b1[c0 * 8];
    short* lB1_1 = &lds_b1[c1 * 8];

    for (int k0 = 0; k0 < K; k0 += 64) {
        __syncthreads();
        async_copy16(a0 + k0, lA0_0);
        async_copy16(a1 + k0, lA0_1);
        async_copy16(b0 + k0, lB0_0);
        async_copy16(b1 + k0, lB0_1);
        async_copy16(a0 + k0 + 32, lA1_0);
        async_copy16(a1 + k0 + 32, lA1_1);
        async_copy16(b0 + k0 + 32, lB1_0);
        async_copy16(b1 + k0 + 32, lB1_1);
        __syncthreads();

        short8 af[4], bfv[4];
#pragma unroll
        for (int i = 0; i < 4; ++i)
            af[i] = *(const short8*)&lds_a0[(wm + i * 16 + l16) * 32 + q * 8];
#pragma unroll
        for (int i = 0; i < 4; ++i)
            bfv[i] = *(const short8*)&lds_b0[(wn + i * 16 + l16) * 32 + q * 8];
#pragma unroll
        for (int mi = 0; mi < 4; ++mi)
#pragma unroll
            for (int ni = 0; ni < 4; ++ni)
                acc[mi][ni] = __builtin_amdgcn_mfma_f32_16x16x32_f16(
                    af[mi], bfv[ni], acc[mi][ni], 0, 0, 0);

#pragma unroll
        for (int i = 0; i < 4; ++i)
            af[i] = *(const short8*)&lds_a1[(wm + i * 16 + l16) * 32 + q * 8];
#pragma unroll
        for (int i = 0; i < 4; ++i)
            bfv[i] = *(const short8*)&lds_b1[(wn + i * 16 + l16) * 32 + q * 8];
#pragma unroll
        for (int mi = 0; mi < 4; ++mi)
#pragma unroll
            for (int ni = 0; ni < 4; ++ni)
                acc[mi][ni] = __builtin_amdgcn_mfma_f32_16x16x32_f16(
                    af[mi], bfv[ni], acc[mi][ni], 0, 0, 0);
    }

    __half* ct = (__half*)smem;
#pragma unroll
    for (int h = 0; h < 2; ++h) {
        __syncthreads();
        if (wm == h * 64) {
#pragma unroll
            for (int ni = 0; ni < 4; ++ni) {
                const int col = wn + ni * 16 + l16;
                const float bv = bias[n0 + col];
#pragma unroll
                for (int mi = 0; mi < 4; ++mi) {
                    const int r0l = mi * 16 + q * 4;
#pragma unroll
                    for (int r = 0; r < 4; ++r) {
                        float v = acc[mi][ni][r] + bv;
                        if (relu_flag) v = fmaxf(v, 0.0f);
                        ct[(r0l + r) * 128 + col] = __float2half(v);
                    }
                }
            }
        }
        __syncthreads();
#pragma unroll
        for (int it = 0; it < 4; ++it) {
            const int chunk = it * 256 + t;
            const int row = chunk >> 4;
            const int off = (chunk & 15) * 8;
            short8 v = *(const short8*)&ct[row * 128 + off];
            *(short8*)&C[(m0 + h * 64 + row) * N + n0 + off] = v;
            if (scores_p) {
                const float* wv = W5g + n0 + off;
                float p = 0.f;
#pragma unroll
                for (int j = 0; j < 8; ++j)
                    p += __half2float(((const __half*)&v)[j]) * wv[j];
#pragma unroll
                for (int o = 8; o > 0; o >>= 1) p += __shfl_down(p, o, 16);
                if (l16 == 0)
                    scores_p[(size_t)bn * M + m0 + h * 64 + row] = p;
            }
        }
    }
}

// ---------------- layer-1 GEMM: K=96, single staging round ----------------

__global__ __launch_bounds__(256, 2)
void gemm_k96(const __half* __restrict__ A, const __half* __restrict__ Bt,
              __half* __restrict__ C, const float* __restrict__ bias, int M, int N)
{
    __shared__ __align__(16) short smem[2 * 128 * 96];
    short* lds_a = smem;
    short* lds_b = smem + 128 * 96;

    const int t   = threadIdx.x;
    const int nbn = N >> 7;
    const int nbm = M >> 7;
    int bm, bn;
    {
        const int b = blockIdx.x;
        if ((nbm & 7) == 0) {
            const int xcd = b & 7;
            const int j   = b >> 3;
            bm = xcd * (nbm >> 3) + j / nbn;
            bn = j % nbn;
        } else {
            bn = b % nbn;
            bm = b / nbn;
        }
    }
    const size_t m0 = (size_t)bm * 128;
    const size_t n0 = (size_t)bn * 128;
    const int wave = t >> 6, lane = t & 63;
    const int wm = (wave >> 1) << 6;
    const int wn = (wave & 1) << 6;
    const int l16 = lane & 15, q = lane >> 4;

#pragma unroll
    for (int i = 0; i < 6; ++i) {
        const int c = i * 256 + t;
        const int r = c / 12, j = c % 12;
        async_copy16(A  + (m0 + (size_t)r) * 96 + j * 8, &lds_a[c * 8]);
        async_copy16(Bt + (n0 + (size_t)r) * 96 + j * 8, &lds_b[c * 8]);
    }
    __syncthreads();

    floatx4 acc[4][4] = {};
#pragma unroll
    for (int ks = 0; ks < 3; ++ks) {
        short8 af[4], bfv[4];
        const int xo = ks * 32 + q * 8;
#pragma unroll
        for (int i = 0; i < 4; ++i)
            af[i] = *(const short8*)&lds_a[(wm + i * 16 + l16) * 96 + xo];
#pragma unroll
        for (int i = 0; i < 4; ++i)
            bfv[i] = *(const short8*)&lds_b[(wn + i * 16 + l16) * 96 + xo];
#pragma unroll
        for (int mi = 0; mi < 4; ++mi)
#pragma unroll
            for (int ni = 0; ni < 4; ++ni)
                acc[mi][ni] = __builtin_amdgcn_mfma_f32_16x16x32_f16(
                    af[mi], bfv[ni], acc[mi][ni], 0, 0, 0);
    }

    __half* ct = (__half*)smem;
#pragma unroll
    for (int h = 0; h < 2; ++h) {
        __syncthreads();
        if (wm == h * 64) {
#pragma unroll
            for (int ni = 0; ni < 4; ++ni) {
                const int col = wn + ni * 16 + l16;
                const float bv = bias[n0 + col];
#pragma unroll
                for (int mi = 0; mi < 4; ++mi) {
                    const int r0l = mi * 16 + q * 4;
#pragma unroll
                    for (int r = 0; r < 4; ++r) {
                        float v = fmaxf(acc[mi][ni][r] + bv, 0.0f);
                        ct[(r0l + r) * 128 + col] = __float2half(v);
                    }
                }
            }
        }
        __syncthreads();
#pragma unroll
        for (int it = 0; it < 4; ++it) {
            const int chunk = it * 256 + t;
            const int row = chunk >> 4;
            const int off = (chunk & 15) * 8;
            *(short8*)&C[(m0 + h * 64 + row) * N + n0 + off] =
                *(const short8*)&ct[row * 128 + off];
        }
    }
}

// ---------------- segment offsets ----------------

__global__ void seg_offsets_kernel(const int* __restrict__ lengths, int* __restrict__ off) {
    if (blockIdx.x == 0 && threadIdx.x == 0) {
        int a = 0;
        off[0] = 0;
        for (int i = 0; i < SEGN; ++i) { a += lengths[i]; off[i + 1] = a; }
    }
}

// ---------------- pooling (4 column-block score partials from gemm256) --------

__global__ __launch_bounds__(256)
void scorepool_kernel(const __half* __restrict__ h4, int slab_beg, int slab_rows,
                      const float* __restrict__ scores_p, const float* __restrict__ b5,
                      const int* __restrict__ segoff,
                      float* __restrict__ pooled, float* __restrict__ denom)
{
    __shared__ float e_sh[FCHUNK];
    const int t = threadIdx.x;
    const int f0 = slab_beg + blockIdx.x * FCHUNK;

    if (t < FCHUNK) {
        const int fl = f0 - slab_beg + t;
        float sc = 0.f;
#pragma unroll
        for (int b = 0; b < 4; ++b) sc += scores_p[(size_t)b * slab_rows + fl];
        sc = fmaxf(sc + b5[0], 0.0f);
        e_sh[t] = __expf(fminf(sc, 80.0f));
    }
    __syncthreads();

    const int c0 = t * 4;
    int lo = 0, hi = SEGN - 1;
    while (lo < hi) {
        int mid = (lo + hi + 1) >> 1;
        if (segoff[mid] <= f0) lo = mid; else hi = mid - 1;
    }
    int s = lo;
    int f = f0;
    const int fend = f0 + FCHUNK;
    const __half* base = h4 + (size_t)(f0 - slab_beg) * HID + c0;
    while (f < fend) {
        int send = segoff[s + 1];
        if (send > fend) send = fend;
        float a0 = 0.f, a1 = 0.f, a2 = 0.f, a3 = 0.f, es = 0.f;
        for (; f < send; ++f, base += HID) {
            float e = e_sh[f - f0];
            const __half2* r2 = (const __half2*)base;
            float2 u = __half22float2(r2[0]);
            float2 v = __half22float2(r2[1]);
            a0 += e * u.x; a1 += e * u.y; a2 += e * v.x; a3 += e * v.y;
            es += e;
        }
        float* p = pooled + (size_t)s * HID + c0;
        atomicAdd(p,     a0);
        atomicAdd(p + 1, a1);
        atomicAdd(p + 2, a2);
        atomicAdd(p + 3, a3);
        if (t == 0) atomicAdd(&denom[s], es);
        ++s;
    }
}

// ---------------- finalize: divide + fp16 ----------------

__global__ __launch_bounds__(256)
void finalize_pool_kernel(const float* __restrict__ pooled, const float* __restrict__ denom,
                          __half* __restrict__ poolh)
{
    int s = blockIdx.x, t = threadIdx.x;
    float inv = 1.0f / denom[s];
    for (int j = t; j < HID; j += 256)
        poolh[(size_t)s * HID + j] = __float2half(pooled[(size_t)s * HID + j] * inv);
}

// ---------------- final head: out = z @ W7 + b7 ----------------

__global__ void final_kernel(const __half* __restrict__ z, const float* __restrict__ W7,
                             const float* __restrict__ b7, float* __restrict__ out) {
    int s = blockIdx.x, t = threadIdx.x;
    float loc[NCLS];
#pragma unroll
    for (int c = 0; c < NCLS; ++c) loc[c] = 0.f;
    for (int k = t; k < HID; k += 256) {
        float zk = __half2float(z[(size_t)s * HID + k]);
        const float* wr = W7 + k * NCLS;
#pragma unroll
        for (int c = 0; c < NCLS; ++c) loc[c] += zk * wr[c];
    }
#pragma unroll
    for (int c = 0; c < NCLS; ++c)
#pragma unroll
        for (int o = 32; o > 0; o >>= 1) loc[c] += __shfl_down(loc[c], o);
    __shared__ float accs[NCLS];
    if (t < NCLS) accs[t] = 0.f;
    __syncthreads();
    if ((t & 63) == 0)
        for (int c = 0; c < NCLS; ++c) atomicAdd(&accs[c], loc[c]);
    __syncthreads();
    if (t < NCLS) out[s * NCLS + t] = accs[t] + b7[t];
}

// ---------------- launch ----------------

extern "C" void kernel_launch(void* const* d_in, const int* in_sizes, int n_in,
                              void* d_out, int out_size, void* d_ws, size_t ws_size,
                              hipStream_t stream) {
    const float* x  = (const float*)d_in[0];
    const float* W1 = (const float*)d_in[1];
    const float* b1 = (const float*)d_in[2];
    const float* W2 = (const float*)d_in[3];
    const float* b2 = (const float*)d_in[4];
    const float* W3 = (const float*)d_in[5];
    const float* b3 = (const float*)d_in[6];
    const float* W4 = (const float*)d_in[7];
    const float* b4 = (const float*)d_in[8];
    const float* W5 = (const float*)d_in[9];
    const float* b5 = (const float*)d_in[10];
    const float* W6 = (const float*)d_in[11];
    const float* b6 = (const float*)d_in[12];
    const float* W7 = (const float*)d_in[13];
    const float* b7 = (const float*)d_in[14];
    const int* lengths = (const int*)d_in[15];
    float* out = (float*)d_out;

    char* ws = (char*)d_ws;
    size_t off = 0;
    auto take = [&](size_t bytes) -> char* {
        char* p = ws + off;
        off = (off + bytes + 255) & ~(size_t)255;
        return p;
    };
    __half* w1t   = (__half*)take((size_t)HID * FPAD * 2);
    __half* w2t   = (__half*)take((size_t)HID * HID * 2);
    __half* w3t   = (__half*)take((size_t)HID * HID * 2);
    __half* w4t   = (__half*)take((size_t)HID * HID * 2);
    __half* w6t   = (__half*)take((size_t)HID * HID * 2);
    int*    segoff = (int*)take((SEGN + 1) * 4);
    float*  pooled = (float*)take((size_t)SEGN * HID * 4);
    float*  denom  = (float*)take(SEGN * 4);
    __half* poolh  = (__half*)take((size_t)SEGN * HID * 2);
    __half* z      = (__half*)take((size_t)SEGN * HID * 2);

    int R = TOTAL;
    while (R > 1024) {
        size_t need = off + (size_t)R * FPAD * 2 + 2 * (size_t)R * HID * 2
                    + (size_t)8 * R * 4 + 4 * 256;
        if (need <= ws_size) break;
        R >>= 1;
    }
    __half* slabX    = (__half*)take((size_t)R * FPAD * 2);
    __half* slabA    = (__half*)take((size_t)R * HID * 2);
    __half* slabB    = (__half*)take((size_t)R * HID * 2);
    float*  scores_p = (float*)take((size_t)8 * R * 4);

    seg_offsets_kernel<<<1, 64, 0, stream>>>(lengths, segoff);
    hipMemsetAsync(pooled, 0, (size_t)SEGN * HID * 4, stream);
    hipMemsetAsync(denom, 0, SEGN * 4, stream);

    conv_wt_kernel<<<(HID * FPAD + 255) / 256, 256, 0, stream>>>(W1, w1t, FEAT, HID, FPAD);
    dim3 gW((HID * HID + 255) / 256, 4);
    conv_w4_kernel<<<gW, 256, 0, stream>>>(W2, W3, W4, W6, w2t, w3t, w4t, w6t);

    const int nBlocksSlab = (R / 128) * (HID / 128);
    const int nBlocks256  = (R / 256) * (HID / 256);
    for (int sb = 0; sb < TOTAL; sb += R) {
        conv_x_slab<<<(R * FPAD + 255) / 256, 256, 0, stream>>>(x, slabX, sb, R);
        gemm_k96<<<nBlocksSlab, 256, 0, stream>>>(slabX, w1t, slabA, b1, R, HID);
        gemm256<<<nBlocks256, 512, 0, stream>>>(slabA, w2t, slabB, b2, R, HID, HID, 1,
                                                nullptr, nullptr);
        gemm256<<<nBlocks256, 512, 0, stream>>>(slabB, w3t, slabA, b3, R, HID, HID, 1,
                                                nullptr, nullptr);
        gemm256<<<nBlocks256, 512, 0, stream>>>(slabA, w4t, slabB, b4, R, HID, HID, 1,
                                                W5, scores_p);
        scorepool_kernel<<<R / FCHUNK, 256, 0, stream>>>(slabB, sb, R, scores_p, b5,
                                                         segoff, pooled, denom);
    }

    finalize_pool_kernel<<<SEGN, 256, 0, stream>>>(pooled, denom, poolh);
    const int nBlocksHead = (SEGN / 128) * (HID / 128);
    gemm_f16<<<nBlocksHead, 256, 0, stream>>>(poolh, w6t, z, b6, SEGN, HID, HID, 1,
                                              nullptr, nullptr);
    final_kernel<<<SEGN, 256, 0, stream>>>(z, W7, b7, out);
}

// Round 4
// 1259.515 us; speedup vs baseline: 1.0062x; 1.0062x over previous
//
#include <hip/hip_runtime.h>
#include <hip/hip_fp16.h>

#define TOTAL 131072
#define SEGN  256
#define FEAT  78
#define FPAD  96
#define HID   1024
#define NCLS  10
#define FCHUNK 32

typedef __attribute__((ext_vector_type(8))) short short8;
typedef __attribute__((ext_vector_type(4))) float floatx4;

typedef __attribute__((address_space(1))) void gvoid_t;
typedef __attribute__((address_space(3))) void svoid_t;

__device__ __forceinline__ void async_copy16(const void* gsrc, void* ldst) {
    __builtin_amdgcn_global_load_lds((gvoid_t*)(void*)gsrc, (svoid_t*)ldst, 16, 0, 0);
}

// ---------------- conversion kernels ----------------

__global__ void conv_x_slab(const float* __restrict__ x, __half* __restrict__ xb,
                            int row0, int rows) {
    int idx = blockIdx.x * 256 + threadIdx.x;
    if (idx >= rows * FPAD) return;
    int col = idx % FPAD;
    int r   = idx / FPAD;
    float v = (col < FEAT) ? x[(size_t)(row0 + r) * FEAT + col] : 0.0f;
    xb[idx] = __float2half(v);
}

__global__ void conv_wt_kernel(const float* __restrict__ W, __half* __restrict__ Wt,
                               int K, int N, int Kpad) {
    int idx = blockIdx.x * 256 + threadIdx.x;
    if (idx >= N * Kpad) return;
    int k = idx % Kpad;
    int n = idx / Kpad;
    float v = (k < K) ? W[(size_t)k * N + n] : 0.0f;
    Wt[idx] = __float2half(v);
}

__global__ void conv_w4_kernel(const float* __restrict__ W2, const float* __restrict__ W3,
                               const float* __restrict__ W4, const float* __restrict__ W6,
                               __half* __restrict__ w2t, __half* __restrict__ w3t,
                               __half* __restrict__ w4t, __half* __restrict__ w6t) {
    int idx = blockIdx.x * 256 + threadIdx.x;
    if (idx >= HID * HID) return;
    int k = idx % HID;
    int n = idx / HID;
    const float* Ws[4] = {W2, W3, W4, W6};
    __half* Ts[4] = {w2t, w3t, w4t, w6t};
    int w = blockIdx.y;
    Ts[w][idx] = __float2half(Ws[w][(size_t)k * HID + n]);
}

// ---------------- 256x256 GEMM, 16 waves / 64KB LDS / high-occupancy --------
// C = act(A @ Bt^T + bias), A[M][K], Bt[N][K] f16, M%256==0, N%256==0, K%32==0,
// K/32 >= 2. 1024 threads = 16 waves (4M x 4N), per-wave 64x64 output
// (acc = 64 regs -> total/wave ~115 <= 128 -> 4 waves/SIMD resident).
// K-sub-tiles of 32, ring-2 LDS (2 x 32KB = 64KB), stage T+1 during T,
// drain vmcnt(0) + ONE barrier per sub-tile; waves drift within the sub-tile
// so ds_read / MFMA / staging of different waves overlap on the CU's pipes.
// LDS slot swizzle: slot ^= (row>>1)&3 applied as inverse perm on the GLOBAL
// source address (global_load_lds writes linearly) + same swizzle on ds_read.
// Optional fused score partials for layer 4: scores_p[bn*M + row].

#define VMCNT0  asm volatile("s_waitcnt vmcnt(0)" ::: "memory")
#define SBAR    __builtin_amdgcn_s_barrier()

#define STAGE(TT) do { short* d_ = smem + (((TT)&1)<<14); \
    async_copy16(gA + (TT)*32, d_ + t*8); \
    async_copy16(gB + (TT)*32, d_ + 8192 + t*8); } while (0)

__global__ __launch_bounds__(1024, 4)
void gemm256(const __half* __restrict__ A, const __half* __restrict__ Bt,
             __half* __restrict__ C, const float* __restrict__ bias,
             int M, int N, int K, int relu_flag,
             const float* __restrict__ W5g, float* __restrict__ scores_p)
{
    __shared__ __align__(16) short smem[2 * 16384];   // 64 KB: 2 x (A 16KB + B 16KB)

    const int t   = threadIdx.x;
    const int nbn = N >> 8;
    const int nbm = M >> 8;
    int bm, bn;
    {
        const int b = blockIdx.x;
        if ((nbm & 7) == 0) {
            const int xcd = b & 7;
            const int j   = b >> 3;
            bm = xcd * (nbm >> 3) + j / nbn;
            bn = j % nbn;
        } else {
            bn = b % nbn;
            bm = b / nbn;
        }
    }
    const size_t m0 = (size_t)bm << 8;
    const size_t n0 = (size_t)bn << 8;
    const int wave = t >> 6, lane = t & 63;
    const int wmb = (wave >> 2) << 6;        // 0 / 64 / 128 / 192
    const int wnb = (wave & 3) << 6;         // 0 / 64 / 128 / 192
    const int l16 = lane & 15, q = lane >> 4;
    const int qa  = q ^ ((l16 >> 1) & 3);    // swizzled k-slot (read side)
    const int aoff = (wmb + l16) * 32 + qa * 8;
    const int boff = (wnb + l16) * 32 + qa * 8;

    // staging: LDS slot p = t; row = p>>2 (0..255), k-slot = p&3;
    // source k-slot = (p&3) ^ ((p>>3)&3)  (inverse of read swizzle)
    const int rr = t >> 2;
    const int qs = ((t & 3) ^ ((t >> 3) & 3)) * 8;
    const __half* gA = A  + (m0 + rr) * K + qs;
    const __half* gB = Bt + (n0 + rr) * K + qs;

    floatx4 acc[4][4] = {};
    const int NT = K >> 5;

    STAGE(0);
    VMCNT0;
    SBAR;

    for (int T = 0; T < NT; ++T) {
        const short* base_ = smem + ((T & 1) << 14);
        short8 af[4], bf[4];
#pragma unroll
        for (int i = 0; i < 4; ++i)
            af[i] = *(const short8*)&base_[aoff + i * 512];
#pragma unroll
        for (int i = 0; i < 4; ++i)
            bf[i] = *(const short8*)&base_[8192 + boff + i * 512];
        if (T < NT - 1) STAGE(T + 1);
        __builtin_amdgcn_s_setprio(1);
#pragma unroll
        for (int mi = 0; mi < 4; ++mi)
#pragma unroll
            for (int ni = 0; ni < 4; ++ni)
                acc[mi][ni] = __builtin_amdgcn_mfma_f32_16x16x32_f16(
                    af[mi], bf[ni], acc[mi][ni], 0, 0, 0);
        __builtin_amdgcn_s_setprio(0);
        VMCNT0;
        SBAR;
    }

    // ---- epilogue: two 128-row halves through LDS, 16B coalesced stores ----
    __half* ct = (__half*)smem;   // 128 x 256 f16 = 64 KB
#pragma unroll
    for (int h = 0; h < 2; ++h) {
        __syncthreads();
        if ((wmb >> 7) == h) {
            const int rbase = (wmb & 127) + q * 4;
#pragma unroll
            for (int ni = 0; ni < 4; ++ni) {
                const int col = wnb + ni * 16 + l16;
                const float bv = bias[n0 + col];
#pragma unroll
                for (int mi = 0; mi < 4; ++mi) {
#pragma unroll
                    for (int r = 0; r < 4; ++r) {
                        float v = acc[mi][ni][r] + bv;
                        if (relu_flag) v = fmaxf(v, 0.0f);
                        ct[(rbase + mi * 16 + r) * 256 + col] = __float2half(v);
                    }
                }
            }
        }
        __syncthreads();
#pragma unroll
        for (int it = 0; it < 4; ++it) {
            const int chunk = it * 1024 + t;
            const int row = chunk >> 5;
            const int c32 = chunk & 31;
            short8 v = *(const short8*)&ct[row * 256 + c32 * 8];
            *(short8*)&C[(m0 + h * 128 + row) * N + n0 + c32 * 8] = v;
            if (scores_p) {
                const float* wv = W5g + n0 + c32 * 8;
                float p = 0.f;
#pragma unroll
                for (int j = 0; j < 8; ++j)
                    p += __half2float(((const __half*)&v)[j]) * wv[j];
#pragma unroll
                for (int o = 16; o > 0; o >>= 1) p += __shfl_down(p, o, 32);
                if ((t & 31) == 0)
                    scores_p[(size_t)bn * M + m0 + h * 128 + row] = p;
            }
        }
    }
}

// ---------------- old 128x128 GEMM (kept for the small head GEMM) ----------

__global__ __launch_bounds__(256, 2)
void gemm_f16(const __half* __restrict__ A, const __half* __restrict__ Bt,
              __half* __restrict__ C, const float* __restrict__ bias,
              int M, int N, int K, int relu_flag,
              const float* __restrict__ W5g, float* __restrict__ scores_p)
{
    __shared__ __align__(16) short smem[4 * 128 * 32];
    short* lds_a0 = smem;
    short* lds_a1 = smem + 128 * 32;
    short* lds_b0 = smem + 2 * 128 * 32;
    short* lds_b1 = smem + 3 * 128 * 32;

    const int t   = threadIdx.x;
    const int nbn = N >> 7;
    const int nbm = M >> 7;
    int bm, bn;
    {
        const int b = blockIdx.x;
        if ((nbm & 7) == 0) {
            const int xcd = b & 7;
            const int j   = b >> 3;
            bm = xcd * (nbm >> 3) + j / nbn;
            bn = j % nbn;
        } else {
            bn = b % nbn;
            bm = b / nbn;
        }
    }
    const size_t m0 = (size_t)bm * 128;
    const size_t n0 = (size_t)bn * 128;
    const int wave = t >> 6, lane = t & 63;
    const int wm = (wave >> 1) << 6;
    const int wn = (wave & 1) << 6;
    const int l16 = lane & 15, q = lane >> 4;

    floatx4 acc[4][4] = {};

    const int c0 = t, c1 = t + 256;
    const __half* a0 = A  + (m0 + (size_t)(c0 >> 2)) * K + (c0 & 3) * 8;
    const __half* a1 = A  + (m0 + (size_t)(c1 >> 2)) * K + (c1 & 3) * 8;
    const __half* b0 = Bt + (n0 + (size_t)(c0 >> 2)) * K + (c0 & 3) * 8;
    const __half* b1 = Bt + (n0 + (size_t)(c1 >> 2)) * K + (c1 & 3) * 8;
    short* lA0_0 = &lds_a0[c0 * 8];
    short* lA0_1 = &lds_a0[c1 * 8];
    short* lA1_0 = &lds_a1[c0 * 8];
    short* lA1_1 = &lds_a1[c1 * 8];
    short* lB0_0 = &lds_b0[c0 * 8];
    short* lB0_1 = &lds_b0[c1 * 8];
    short* lB1_0 = &lds_b1[c0 * 8];
    short* lB1_1 = &lds_b1[c1 * 8];

    for (int k0 = 0; k0 < K; k0 += 64) {
        __syncthreads();
        async_copy16(a0 + k0, lA0_0);
        async_copy16(a1 + k0, lA0_1);
        async_copy16(b0 + k0, lB0_0);
        async_copy16(b1 + k0, lB0_1);
        async_copy16(a0 + k0 + 32, lA1_0);
        async_copy16(a1 + k0 + 32, lA1_1);
        async_copy16(b0 + k0 + 32, lB1_0);
        async_copy16(b1 + k0 + 32, lB1_1);
        __syncthreads();

        short8 af[4], bfv[4];
#pragma unroll
        for (int i = 0; i < 4; ++i)
            af[i] = *(const short8*)&lds_a0[(wm + i * 16 + l16) * 32 + q * 8];
#pragma unroll
        for (int i = 0; i < 4; ++i)
            bfv[i] = *(const short8*)&lds_b0[(wn + i * 16 + l16) * 32 + q * 8];
#pragma unroll
        for (int mi = 0; mi < 4; ++mi)
#pragma unroll
            for (int ni = 0; ni < 4; ++ni)
                acc[mi][ni] = __builtin_amdgcn_mfma_f32_16x16x32_f16(
                    af[mi], bfv[ni], acc[mi][ni], 0, 0, 0);

#pragma unroll
        for (int i = 0; i < 4; ++i)
            af[i] = *(const short8*)&lds_a1[(wm + i * 16 + l16) * 32 + q * 8];
#pragma unroll
        for (int i = 0; i < 4; ++i)
            bfv[i] = *(const short8*)&lds_b1[(wn + i * 16 + l16) * 32 + q * 8];
#pragma unroll
        for (int mi = 0; mi < 4; ++mi)
#pragma unroll
            for (int ni = 0; ni < 4; ++ni)
                acc[mi][ni] = __builtin_amdgcn_mfma_f32_16x16x32_f16(
                    af[mi], bfv[ni], acc[mi][ni], 0, 0, 0);
    }

    __half* ct = (__half*)smem;
#pragma unroll
    for (int h = 0; h < 2; ++h) {
        __syncthreads();
        if (wm == h * 64) {
#pragma unroll
            for (int ni = 0; ni < 4; ++ni) {
                const int col = wn + ni * 16 + l16;
                const float bv = bias[n0 + col];
#pragma unroll
                for (int mi = 0; mi < 4; ++mi) {
                    const int r0l = mi * 16 + q * 4;
#pragma unroll
                    for (int r = 0; r < 4; ++r) {
                        float v = acc[mi][ni][r] + bv;
                        if (relu_flag) v = fmaxf(v, 0.0f);
                        ct[(r0l + r) * 128 + col] = __float2half(v);
                    }
                }
            }
        }
        __syncthreads();
#pragma unroll
        for (int it = 0; it < 4; ++it) {
            const int chunk = it * 256 + t;
            const int row = chunk >> 4;
            const int off = (chunk & 15) * 8;
            short8 v = *(const short8*)&ct[row * 128 + off];
            *(short8*)&C[(m0 + h * 64 + row) * N + n0 + off] = v;
            if (scores_p) {
                const float* wv = W5g + n0 + off;
                float p = 0.f;
#pragma unroll
                for (int j = 0; j < 8; ++j)
                    p += __half2float(((const __half*)&v)[j]) * wv[j];
#pragma unroll
                for (int o = 8; o > 0; o >>= 1) p += __shfl_down(p, o, 16);
                if (l16 == 0)
                    scores_p[(size_t)bn * M + m0 + h * 64 + row] = p;
            }
        }
    }
}

// ---------------- layer-1 GEMM: K=96, single staging round ----------------

__global__ __launch_bounds__(256, 2)
void gemm_k96(const __half* __restrict__ A, const __half* __restrict__ Bt,
              __half* __restrict__ C, const float* __restrict__ bias, int M, int N)
{
    __shared__ __align__(16) short smem[2 * 128 * 96];
    short* lds_a = smem;
    short* lds_b = smem + 128 * 96;

    const int t   = threadIdx.x;
    const int nbn = N >> 7;
    const int nbm = M >> 7;
    int bm, bn;
    {
        const int b = blockIdx.x;
        if ((nbm & 7) == 0) {
            const int xcd = b & 7;
            const int j   = b >> 3;
            bm = xcd * (nbm >> 3) + j / nbn;
            bn = j % nbn;
        } else {
            bn = b % nbn;
            bm = b / nbn;
        }
    }
    const size_t m0 = (size_t)bm * 128;
    const size_t n0 = (size_t)bn * 128;
    const int wave = t >> 6, lane = t & 63;
    const int wm = (wave >> 1) << 6;
    const int wn = (wave & 1) << 6;
    const int l16 = lane & 15, q = lane >> 4;

#pragma unroll
    for (int i = 0; i < 6; ++i) {
        const int c = i * 256 + t;
        const int r = c / 12, j = c % 12;
        async_copy16(A  + (m0 + (size_t)r) * 96 + j * 8, &lds_a[c * 8]);
        async_copy16(Bt + (n0 + (size_t)r) * 96 + j * 8, &lds_b[c * 8]);
    }
    __syncthreads();

    floatx4 acc[4][4] = {};
#pragma unroll
    for (int ks = 0; ks < 3; ++ks) {
        short8 af[4], bfv[4];
        const int xo = ks * 32 + q * 8;
#pragma unroll
        for (int i = 0; i < 4; ++i)
            af[i] = *(const short8*)&lds_a[(wm + i * 16 + l16) * 96 + xo];
#pragma unroll
        for (int i = 0; i < 4; ++i)
            bfv[i] = *(const short8*)&lds_b[(wn + i * 16 + l16) * 96 + xo];
#pragma unroll
        for (int mi = 0; mi < 4; ++mi)
#pragma unroll
            for (int ni = 0; ni < 4; ++ni)
                acc[mi][ni] = __builtin_amdgcn_mfma_f32_16x16x32_f16(
                    af[mi], bfv[ni], acc[mi][ni], 0, 0, 0);
    }

    __half* ct = (__half*)smem;
#pragma unroll
    for (int h = 0; h < 2; ++h) {
        __syncthreads();
        if (wm == h * 64) {
#pragma unroll
            for (int ni = 0; ni < 4; ++ni) {
                const int col = wn + ni * 16 + l16;
                const float bv = bias[n0 + col];
#pragma unroll
                for (int mi = 0; mi < 4; ++mi) {
                    const int r0l = mi * 16 + q * 4;
#pragma unroll
                    for (int r = 0; r < 4; ++r) {
                        float v = fmaxf(acc[mi][ni][r] + bv, 0.0f);
                        ct[(r0l + r) * 128 + col] = __float2half(v);
                    }
                }
            }
        }
        __syncthreads();
#pragma unroll
        for (int it = 0; it < 4; ++it) {
            const int chunk = it * 256 + t;
            const int row = chunk >> 4;
            const int off = (chunk & 15) * 8;
            *(short8*)&C[(m0 + h * 64 + row) * N + n0 + off] =
                *(const short8*)&ct[row * 128 + off];
        }
    }
}

// ---------------- segment offsets ----------------

__global__ void seg_offsets_kernel(const int* __restrict__ lengths, int* __restrict__ off) {
    if (blockIdx.x == 0 && threadIdx.x == 0) {
        int a = 0;
        off[0] = 0;
        for (int i = 0; i < SEGN; ++i) { a += lengths[i]; off[i + 1] = a; }
    }
}

// ---------------- pooling (4 column-block score partials from gemm256) --------

__global__ __launch_bounds__(256)
void scorepool_kernel(const __half* __restrict__ h4, int slab_beg, int slab_rows,
                      const float* __restrict__ scores_p, const float* __restrict__ b5,
                      const int* __restrict__ segoff,
                      float* __restrict__ pooled, float* __restrict__ denom)
{
    __shared__ float e_sh[FCHUNK];
    const int t = threadIdx.x;
    const int f0 = slab_beg + blockIdx.x * FCHUNK;

    if (t < FCHUNK) {
        const int fl = f0 - slab_beg + t;
        float sc = 0.f;
#pragma unroll
        for (int b = 0; b < 4; ++b) sc += scores_p[(size_t)b * slab_rows + fl];
        sc = fmaxf(sc + b5[0], 0.0f);
        e_sh[t] = __expf(fminf(sc, 80.0f));
    }
    __syncthreads();

    const int c0 = t * 4;
    int lo = 0, hi = SEGN - 1;
    while (lo < hi) {
        int mid = (lo + hi + 1) >> 1;
        if (segoff[mid] <= f0) lo = mid; else hi = mid - 1;
    }
    int s = lo;
    int f = f0;
    const int fend = f0 + FCHUNK;
    const __half* base = h4 + (size_t)(f0 - slab_beg) * HID + c0;
    while (f < fend) {
        int send = segoff[s + 1];
        if (send > fend) send = fend;
        float a0 = 0.f, a1 = 0.f, a2 = 0.f, a3 = 0.f, es = 0.f;
        for (; f < send; ++f, base += HID) {
            float e = e_sh[f - f0];
            const __half2* r2 = (const __half2*)base;
            float2 u = __half22float2(r2[0]);
            float2 v = __half22float2(r2[1]);
            a0 += e * u.x; a1 += e * u.y; a2 += e * v.x; a3 += e * v.y;
            es += e;
        }
        float* p = pooled + (size_t)s * HID + c0;
        atomicAdd(p,     a0);
        atomicAdd(p + 1, a1);
        atomicAdd(p + 2, a2);
        atomicAdd(p + 3, a3);
        if (t == 0) atomicAdd(&denom[s], es);
        ++s;
    }
}

// ---------------- finalize: divide + fp16 ----------------

__global__ __launch_bounds__(256)
void finalize_pool_kernel(const float* __restrict__ pooled, const float* __restrict__ denom,
                          __half* __restrict__ poolh)
{
    int s = blockIdx.x, t = threadIdx.x;
    float inv = 1.0f / denom[s];
    for (int j = t; j < HID; j += 256)
        poolh[(size_t)s * HID + j] = __float2half(pooled[(size_t)s * HID + j] * inv);
}

// ---------------- final head: out = z @ W7 + b7 ----------------

__global__ void final_kernel(const __half* __restrict__ z, const float* __restrict__ W7,
                             const float* __restrict__ b7, float* __restrict__ out) {
    int s = blockIdx.x, t = threadIdx.x;
    float loc[NCLS];
#pragma unroll
    for (int c = 0; c < NCLS; ++c) loc[c] = 0.f;
    for (int k = t; k < HID; k += 256) {
        float zk = __half2float(z[(size_t)s * HID + k]);
        const float* wr = W7 + k * NCLS;
#pragma unroll
        for (int c = 0; c < NCLS; ++c) loc[c] += zk * wr[c];
    }
#pragma unroll
    for (int c = 0; c < NCLS; ++c)
#pragma unroll
        for (int o = 32; o > 0; o >>= 1) loc[c] += __shfl_down(loc[c], o);
    __shared__ float accs[NCLS];
    if (t < NCLS) accs[t] = 0.f;
    __syncthreads();
    if ((t & 63) == 0)
        for (int c = 0; c < NCLS; ++c) atomicAdd(&accs[c], loc[c]);
    __syncthreads();
    if (t < NCLS) out[s * NCLS + t] = accs[t] + b7[t];
}

// ---------------- launch ----------------

extern "C" void kernel_launch(void* const* d_in, const int* in_sizes, int n_in,
                              void* d_out, int out_size, void* d_ws, size_t ws_size,
                              hipStream_t stream) {
    const float* x  = (const float*)d_in[0];
    const float* W1 = (const float*)d_in[1];
    const float* b1 = (const float*)d_in[2];
    const float* W2 = (const float*)d_in[3];
    const float* b2 = (const float*)d_in[4];
    const float* W3 = (const float*)d_in[5];
    const float* b3 = (const float*)d_in[6];
    const float* W4 = (const float*)d_in[7];
    const float* b4 = (const float*)d_in[8];
    const float* W5 = (const float*)d_in[9];
    const float* b5 = (const float*)d_in[10];
    const float* W6 = (const float*)d_in[11];
    const float* b6 = (const float*)d_in[12];
    const float* W7 = (const float*)d_in[13];
    const float* b7 = (const float*)d_in[14];
    const int* lengths = (const int*)d_in[15];
    float* out = (float*)d_out;

    char* ws = (char*)d_ws;
    size_t off = 0;
    auto take = [&](size_t bytes) -> char* {
        char* p = ws + off;
        off = (off + bytes + 255) & ~(size_t)255;
        return p;
    };
    __half* w1t   = (__half*)take((size_t)HID * FPAD * 2);
    __half* w2t   = (__half*)take((size_t)HID * HID * 2);
    __half* w3t   = (__half*)take((size_t)HID * HID * 2);
    __half* w4t   = (__half*)take((size_t)HID * HID * 2);
    __half* w6t   = (__half*)take((size_t)HID * HID * 2);
    int*    segoff = (int*)take((SEGN + 1) * 4);
    float*  pooled = (float*)take((size_t)SEGN * HID * 4);
    float*  denom  = (float*)take(SEGN * 4);
    __half* poolh  = (__half*)take((size_t)SEGN * HID * 2);
    __half* z      = (__half*)take((size_t)SEGN * HID * 2);

    int R = TOTAL;
    while (R > 1024) {
        size_t need = off + (size_t)R * FPAD * 2 + 2 * (size_t)R * HID * 2
                    + (size_t)8 * R * 4 + 4 * 256;
        if (need <= ws_size) break;
        R >>= 1;
    }
    __half* slabX    = (__half*)take((size_t)R * FPAD * 2);
    __half* slabA    = (__half*)take((size_t)R * HID * 2);
    __half* slabB    = (__half*)take((size_t)R * HID * 2);
    float*  scores_p = (float*)take((size_t)8 * R * 4);

    seg_offsets_kernel<<<1, 64, 0, stream>>>(lengths, segoff);
    hipMemsetAsync(pooled, 0, (size_t)SEGN * HID * 4, stream);
    hipMemsetAsync(denom, 0, SEGN * 4, stream);

    conv_wt_kernel<<<(HID * FPAD + 255) / 256, 256, 0, stream>>>(W1, w1t, FEAT, HID, FPAD);
    dim3 gW((HID * HID + 255) / 256, 4);
    conv_w4_kernel<<<gW, 256, 0, stream>>>(W2, W3, W4, W6, w2t, w3t, w4t, w6t);

    const int nBlocksSlab = (R / 128) * (HID / 128);
    const int nBlocks256  = (R / 256) * (HID / 256);
    for (int sb = 0; sb < TOTAL; sb += R) {
        conv_x_slab<<<(R * FPAD + 255) / 256, 256, 0, stream>>>(x, slabX, sb, R);
        gemm_k96<<<nBlocksSlab, 256, 0, stream>>>(slabX, w1t, slabA, b1, R, HID);
        gemm256<<<nBlocks256, 1024, 0, stream>>>(slabA, w2t, slabB, b2, R, HID, HID, 1,
                                                 nullptr, nullptr);
        gemm256<<<nBlocks256, 1024, 0, stream>>>(slabB, w3t, slabA, b3, R, HID, HID, 1,
                                                 nullptr, nullptr);
        gemm256<<<nBlocks256, 1024, 0, stream>>>(slabA, w4t, slabB, b4, R, HID, HID, 1,
                                                 W5, scores_p);
        scorepool_kernel<<<R / FCHUNK, 256, 0, stream>>>(slabB, sb, R, scores_p, b5,
                                                         segoff, pooled, denom);
    }

    finalize_pool_kernel<<<SEGN, 256, 0, stream>>>(pooled, denom, poolh);
    const int nBlocksHead = (SEGN / 128) * (HID / 128);
    gemm_f16<<<nBlocksHead, 256, 0, stream>>>(poolh, w6t, z, b6, SEGN, HID, HID, 1,
                                              nullptr, nullptr);
    final_kernel<<<SEGN, 256, 0, stream>>>(z, W7, b7, out);
}

// Round 5
// 1189.066 us; speedup vs baseline: 1.0658x; 1.0592x over previous
//
#include <hip/hip_runtime.h>
#include <hip/hip_fp16.h>

#define TOTAL 131072
#define SEGN  256
#define FEAT  78
#define FPAD  96
#define HID   1024
#define NCLS  10
#define FCHUNK 32

typedef __attribute__((ext_vector_type(8))) short short8;
typedef __attribute__((ext_vector_type(4))) float floatx4;

typedef __attribute__((address_space(1))) void gvoid_t;
typedef __attribute__((address_space(3))) void svoid_t;

__device__ __forceinline__ void async_copy16(const void* gsrc, void* ldst) {
    __builtin_amdgcn_global_load_lds((gvoid_t*)(void*)gsrc, (svoid_t*)ldst, 16, 0, 0);
}

// ---------------- conversion kernels ----------------

__global__ void conv_x_slab(const float* __restrict__ x, __half* __restrict__ xb,
                            int row0, int rows) {
    int idx = blockIdx.x * 256 + threadIdx.x;
    if (idx >= rows * FPAD) return;
    int col = idx % FPAD;
    int r   = idx / FPAD;
    float v = (col < FEAT) ? x[(size_t)(row0 + r) * FEAT + col] : 0.0f;
    xb[idx] = __float2half(v);
}

__global__ void conv_wt_kernel(const float* __restrict__ W, __half* __restrict__ Wt,
                               int K, int N, int Kpad) {
    int idx = blockIdx.x * 256 + threadIdx.x;
    if (idx >= N * Kpad) return;
    int k = idx % Kpad;
    int n = idx / Kpad;
    float v = (k < K) ? W[(size_t)k * N + n] : 0.0f;
    Wt[idx] = __float2half(v);
}

__global__ void conv_w4_kernel(const float* __restrict__ W2, const float* __restrict__ W3,
                               const float* __restrict__ W4, const float* __restrict__ W6,
                               __half* __restrict__ w2t, __half* __restrict__ w3t,
                               __half* __restrict__ w4t, __half* __restrict__ w6t) {
    int idx = blockIdx.x * 256 + threadIdx.x;
    if (idx >= HID * HID) return;
    int k = idx % HID;
    int n = idx / HID;
    const float* Ws[4] = {W2, W3, W4, W6};
    __half* Ts[4] = {w2t, w3t, w4t, w6t};
    int w = blockIdx.y;
    Ts[w][idx] = __float2half(Ws[w][(size_t)k * HID + n]);
}

// ---------------- 256x256 GEMM, register-double-buffered fragments ----------
// C = act(A @ Bt^T + bias), A[M][K], Bt[N][K] f16, M%256==0, N%256==0,
// K%64==0, K/32 >= 4 even. 512 threads = 8 waves (2M x 4N), per-wave 128x64.
// K-sub-tiles of 32, ring-4 LDS (4 x 32KB), staging distance 3, vmcnt(2)
// per iter (counted; drains only in tail).
// KEY: fragment REGISTER double-buffer (f0/f1). Iter T reads tile T+1's
// fragments into the alternate set while the MFMAs consume tile T's set,
// whose ds_reads were issued a full iteration earlier -> the MFMA stream
// never stalls on its own read burst, LDS pipe and MFMA pipe overlap
// WITHIN each wave (immune to barrier phasing, which flattened R0-R3).
// Race safety: reads of tile T+1 coexist only with DMA for tiles T+2/T+3
// (different ring slots); slot reuse (tile T+5) is issued only after the
// barrier that proves every wave's MFMA(T+1) lgkm-wait retired its reads.
// LDS slot swizzle: slot ^= (row>>1)&3 as inverse perm on the GLOBAL source
// address + same swizzle on ds_read. Optional fused layer-4 score partials.

#define VMCNT(n)  asm volatile("s_waitcnt vmcnt(" #n ")" ::: "memory")
#define SBAR      __builtin_amdgcn_s_barrier()

#define STAGE(TT) do { short* d_ = smem + (((TT)&3)<<14); \
    async_copy16(gA + (TT)*32,           d_ + t*8); \
    async_copy16(gA + (TT)*32 + kstr128, d_ + 4096 + t*8); \
    async_copy16(gB + (TT)*32,           d_ + 8192 + t*8); \
    async_copy16(gB + (TT)*32 + kstr128, d_ + 12288 + t*8); } while (0)

#define READF(S, TT) do { \
    const short* base_ = smem + (((TT)&3)<<14); \
    _Pragma("unroll") \
    for (int i_ = 0; i_ < 4; ++i_) S##_a0[i_] = *(const short8*)&base_[aoff + i_*512]; \
    _Pragma("unroll") \
    for (int i_ = 0; i_ < 4; ++i_) S##_a1[i_] = *(const short8*)&base_[2048 + aoff + i_*512]; \
    _Pragma("unroll") \
    for (int i_ = 0; i_ < 4; ++i_) S##_b[i_]  = *(const short8*)&base_[8192 + boff + i_*512]; \
} while (0)

#define MFMA32(S) do { \
    __builtin_amdgcn_s_setprio(1); \
    _Pragma("unroll") \
    for (int mi_ = 0; mi_ < 4; ++mi_) \
        _Pragma("unroll") \
        for (int ni_ = 0; ni_ < 4; ++ni_) \
            acc[mi_][ni_] = __builtin_amdgcn_mfma_f32_16x16x32_f16( \
                S##_a0[mi_], S##_b[ni_], acc[mi_][ni_], 0, 0, 0); \
    _Pragma("unroll") \
    for (int mi_ = 0; mi_ < 4; ++mi_) \
        _Pragma("unroll") \
        for (int ni_ = 0; ni_ < 4; ++ni_) \
            acc[4+mi_][ni_] = __builtin_amdgcn_mfma_f32_16x16x32_f16( \
                S##_a1[mi_], S##_b[ni_], acc[4+mi_][ni_], 0, 0, 0); \
    __builtin_amdgcn_s_setprio(0); \
} while (0)

__global__ __launch_bounds__(512, 2)
void gemm256(const __half* __restrict__ A, const __half* __restrict__ Bt,
             __half* __restrict__ C, const float* __restrict__ bias,
             int M, int N, int K, int relu_flag,
             const float* __restrict__ W5g, float* __restrict__ scores_p)
{
    __shared__ __align__(16) short smem[4 * 16384];   // 128 KB: 4 x (A 16KB + B 16KB)

    const int t   = threadIdx.x;
    const int nbn = N >> 8;
    const int nbm = M >> 8;
    int bm, bn;
    {
        const int b = blockIdx.x;
        if ((nbm & 7) == 0) {
            const int xcd = b & 7;
            const int j   = b >> 3;
            bm = xcd * (nbm >> 3) + j / nbn;
            bn = j % nbn;
        } else {
            bn = b % nbn;
            bm = b / nbn;
        }
    }
    const size_t m0 = (size_t)bm << 8;
    const size_t n0 = (size_t)bn << 8;
    const int wave = t >> 6, lane = t & 63;
    const int wmb = (wave >> 2) << 7;        // 0 / 128
    const int wnb = (wave & 3) << 6;         // 0 / 64 / 128 / 192
    const int l16 = lane & 15, q = lane >> 4;
    const int qa  = q ^ ((l16 >> 1) & 3);    // swizzled k-slot (read side)
    const int aoff = (wmb + l16) * 32 + qa * 8;
    const int boff = (wnb + l16) * 32 + qa * 8;

    // staging: linear LDS slot p = load*512 + t; row = p>>2;
    // source k-slot = (p&3) ^ ((p>>3)&3)  (inverse of read swizzle)
    const int rr = t >> 2;
    const int qs = ((t & 3) ^ ((t >> 3) & 3)) * 8;
    const __half* gA = A  + (m0 + rr) * K + qs;
    const __half* gB = Bt + (n0 + rr) * K + qs;
    const int kstr128 = K << 7;              // +128 rows

    floatx4 acc[8][4] = {};
    short8 f0_a0[4], f0_a1[4], f0_b[4];
    short8 f1_a0[4], f1_a1[4], f1_b[4];
    const int NT = K >> 5;                   // even, >= 4

    // prologue: tiles 0,1,2 staged (12 DMA); retire tile 0; read its frags
    STAGE(0); STAGE(1); STAGE(2);
    VMCNT(8);
    SBAR;
    READF(f0, 0);

    int T = 0;
    for (; T < NT - 3; T += 2) {
        VMCNT(4);                    // outstanding {T+1,T+2}: retire T+1
        SBAR;
        READF(f1, T + 1);            // overlaps MFMA below (next-iter data)
        STAGE(T + 3);
        MFMA32(f0);                  // tile T: reads issued last iter, no stall
        VMCNT(4);                    // outstanding {T+2,T+3}: retire T+2
        SBAR;
        READF(f0, T + 2);
        if (T + 4 < NT) STAGE(T + 4);
        MFMA32(f1);                  // tile T+1
    }
    // tail: T == NT-2; only stage NT-1 outstanding
    VMCNT(0);
    SBAR;
    READF(f1, NT - 1);
    MFMA32(f0);                      // tile NT-2
    MFMA32(f1);                      // tile NT-1
    __syncthreads();

    // ---- epilogue: full 256x256 tile through LDS, 16B coalesced stores ----
    __half* ct = (__half*)smem;
#pragma unroll
    for (int ni = 0; ni < 4; ++ni) {
        const int col = wnb + ni * 16 + l16;
        const float bv = bias[n0 + col];
#pragma unroll
        for (int mi = 0; mi < 8; ++mi) {
            const int r0l = wmb + mi * 16 + q * 4;
#pragma unroll
            for (int r = 0; r < 4; ++r) {
                float v = acc[mi][ni][r] + bv;
                if (relu_flag) v = fmaxf(v, 0.0f);
                ct[(r0l + r) * 256 + col] = __float2half(v);
            }
        }
    }
    __syncthreads();
#pragma unroll
    for (int it = 0; it < 16; ++it) {
        const int chunk = it * 512 + t;
        const int row = chunk >> 5;
        const int c32 = chunk & 31;
        short8 v = *(const short8*)&ct[row * 256 + c32 * 8];
        *(short8*)&C[(m0 + row) * N + n0 + c32 * 8] = v;
        if (scores_p) {
            const float* wv = W5g + n0 + c32 * 8;
            float p = 0.f;
#pragma unroll
            for (int j = 0; j < 8; ++j)
                p += __half2float(((const __half*)&v)[j]) * wv[j];
#pragma unroll
            for (int o = 16; o > 0; o >>= 1) p += __shfl_down(p, o, 32);
            if ((t & 31) == 0)
                scores_p[(size_t)bn * M + m0 + row] = p;
        }
    }
}

// ---------------- old 128x128 GEMM (kept for the small head GEMM) ----------

__global__ __launch_bounds__(256, 2)
void gemm_f16(const __half* __restrict__ A, const __half* __restrict__ Bt,
              __half* __restrict__ C, const float* __restrict__ bias,
              int M, int N, int K, int relu_flag,
              const float* __restrict__ W5g, float* __restrict__ scores_p)
{
    __shared__ __align__(16) short smem[4 * 128 * 32];
    short* lds_a0 = smem;
    short* lds_a1 = smem + 128 * 32;
    short* lds_b0 = smem + 2 * 128 * 32;
    short* lds_b1 = smem + 3 * 128 * 32;

    const int t   = threadIdx.x;
    const int nbn = N >> 7;
    const int nbm = M >> 7;
    int bm, bn;
    {
        const int b = blockIdx.x;
        if ((nbm & 7) == 0) {
            const int xcd = b & 7;
            const int j   = b >> 3;
            bm = xcd * (nbm >> 3) + j / nbn;
            bn = j % nbn;
        } else {
            bn = b % nbn;
            bm = b / nbn;
        }
    }
    const size_t m0 = (size_t)bm * 128;
    const size_t n0 = (size_t)bn * 128;
    const int wave = t >> 6, lane = t & 63;
    const int wm = (wave >> 1) << 6;
    const int wn = (wave & 1) << 6;
    const int l16 = lane & 15, q = lane >> 4;

    floatx4 acc[4][4] = {};

    const int c0 = t, c1 = t + 256;
    const __half* a0 = A  + (m0 + (size_t)(c0 >> 2)) * K + (c0 & 3) * 8;
    const __half* a1 = A  + (m0 + (size_t)(c1 >> 2)) * K + (c1 & 3) * 8;
    const __half* b0 = Bt + (n0 + (size_t)(c0 >> 2)) * K + (c0 & 3) * 8;
    const __half* b1 = Bt + (n0 + (size_t)(c1 >> 2)) * K + (c1 & 3) * 8;
    short* lA0_0 = &lds_a0[c0 * 8];
    short* lA0_1 = &lds_a0[c1 * 8];
    short* lA1_0 = &lds_a1[c0 * 8];
    short* lA1_1 = &lds_a1[c1 * 8];
    short* lB0_0 = &lds_b0[c0 * 8];
    short* lB0_1 = &lds_b0[c1 * 8];
    short* lB1_0 = &lds_b1[c0 * 8];
    short* lB1_1 = &lds_b1[c1 * 8];

    for (int k0 = 0; k0 < K; k0 += 64) {
        __syncthreads();
        async_copy16(a0 + k0, lA0_0);
        async_copy16(a1 + k0, lA0_1);
        async_copy16(b0 + k0, lB0_0);
        async_copy16(b1 + k0, lB0_1);
        async_copy16(a0 + k0 + 32, lA1_0);
        async_copy16(a1 + k0 + 32, lA1_1);
        async_copy16(b0 + k0 + 32, lB1_0);
        async_copy16(b1 + k0 + 32, lB1_1);
        __syncthreads();

        short8 af[4], bfv[4];
#pragma unroll
        for (int i = 0; i < 4; ++i)
            af[i] = *(const short8*)&lds_a0[(wm + i * 16 + l16) * 32 + q * 8];
#pragma unroll
        for (int i = 0; i < 4; ++i)
            bfv[i] = *(const short8*)&lds_b0[(wn + i * 16 + l16) * 32 + q * 8];
#pragma unroll
        for (int mi = 0; mi < 4; ++mi)
#pragma unroll
            for (int ni = 0; ni < 4; ++ni)
                acc[mi][ni] = __builtin_amdgcn_mfma_f32_16x16x32_f16(
                    af[mi], bfv[ni], acc[mi][ni], 0, 0, 0);

#pragma unroll
        for (int i = 0; i < 4; ++i)
            af[i] = *(const short8*)&lds_a1[(wm + i * 16 + l16) * 32 + q * 8];
#pragma unroll
        for (int i = 0; i < 4; ++i)
            bfv[i] = *(const short8*)&lds_b1[(wn + i * 16 + l16) * 32 + q * 8];
#pragma unroll
        for (int mi = 0; mi < 4; ++mi)
#pragma unroll
            for (int ni = 0; ni < 4; ++ni)
                acc[mi][ni] = __builtin_amdgcn_mfma_f32_16x16x32_f16(
                    af[mi], bfv[ni], acc[mi][ni], 0, 0, 0);
    }

    __half* ct = (__half*)smem;
#pragma unroll
    for (int h = 0; h < 2; ++h) {
        __syncthreads();
        if (wm == h * 64) {
#pragma unroll
            for (int ni = 0; ni < 4; ++ni) {
                const int col = wn + ni * 16 + l16;
                const float bv = bias[n0 + col];
#pragma unroll
                for (int mi = 0; mi < 4; ++mi) {
                    const int r0l = mi * 16 + q * 4;
#pragma unroll
                    for (int r = 0; r < 4; ++r) {
                        float v = acc[mi][ni][r] + bv;
                        if (relu_flag) v = fmaxf(v, 0.0f);
                        ct[(r0l + r) * 128 + col] = __float2half(v);
                    }
                }
            }
        }
        __syncthreads();
#pragma unroll
        for (int it = 0; it < 4; ++it) {
            const int chunk = it * 256 + t;
            const int row = chunk >> 4;
            const int off = (chunk & 15) * 8;
            short8 v = *(const short8*)&ct[row * 128 + off];
            *(short8*)&C[(m0 + h * 64 + row) * N + n0 + off] = v;
            if (scores_p) {
                const float* wv = W5g + n0 + off;
                float p = 0.f;
#pragma unroll
                for (int j = 0; j < 8; ++j)
                    p += __half2float(((const __half*)&v)[j]) * wv[j];
#pragma unroll
                for (int o = 8; o > 0; o >>= 1) p += __shfl_down(p, o, 16);
                if (l16 == 0)
                    scores_p[(size_t)bn * M + m0 + h * 64 + row] = p;
            }
        }
    }
}

// ---------------- layer-1 GEMM: K=96, single staging round ----------------

__global__ __launch_bounds__(256, 2)
void gemm_k96(const __half* __restrict__ A, const __half* __restrict__ Bt,
              __half* __restrict__ C, const float* __restrict__ bias, int M, int N)
{
    __shared__ __align__(16) short smem[2 * 128 * 96];
    short* lds_a = smem;
    short* lds_b = smem + 128 * 96;

    const int t   = threadIdx.x;
    const int nbn = N >> 7;
    const int nbm = M >> 7;
    int bm, bn;
    {
        const int b = blockIdx.x;
        if ((nbm & 7) == 0) {
            const int xcd = b & 7;
            const int j   = b >> 3;
            bm = xcd * (nbm >> 3) + j / nbn;
            bn = j % nbn;
        } else {
            bn = b % nbn;
            bm = b / nbn;
        }
    }
    const size_t m0 = (size_t)bm * 128;
    const size_t n0 = (size_t)bn * 128;
    const int wave = t >> 6, lane = t & 63;
    const int wm = (wave >> 1) << 6;
    const int wn = (wave & 1) << 6;
    const int l16 = lane & 15, q = lane >> 4;

#pragma unroll
    for (int i = 0; i < 6; ++i) {
        const int c = i * 256 + t;
        const int r = c / 12, j = c % 12;
        async_copy16(A  + (m0 + (size_t)r) * 96 + j * 8, &lds_a[c * 8]);
        async_copy16(Bt + (n0 + (size_t)r) * 96 + j * 8, &lds_b[c * 8]);
    }
    __syncthreads();

    floatx4 acc[4][4] = {};
#pragma unroll
    for (int ks = 0; ks < 3; ++ks) {
        short8 af[4], bfv[4];
        const int xo = ks * 32 + q * 8;
#pragma unroll
        for (int i = 0; i < 4; ++i)
            af[i] = *(const short8*)&lds_a[(wm + i * 16 + l16) * 96 + xo];
#pragma unroll
        for (int i = 0; i < 4; ++i)
            bfv[i] = *(const short8*)&lds_b[(wn + i * 16 + l16) * 96 + xo];
#pragma unroll
        for (int mi = 0; mi < 4; ++mi)
#pragma unroll
            for (int ni = 0; ni < 4; ++ni)
                acc[mi][ni] = __builtin_amdgcn_mfma_f32_16x16x32_f16(
                    af[mi], bfv[ni], acc[mi][ni], 0, 0, 0);
    }

    __half* ct = (__half*)smem;
#pragma unroll
    for (int h = 0; h < 2; ++h) {
        __syncthreads();
        if (wm == h * 64) {
#pragma unroll
            for (int ni = 0; ni < 4; ++ni) {
                const int col = wn + ni * 16 + l16;
                const float bv = bias[n0 + col];
#pragma unroll
                for (int mi = 0; mi < 4; ++mi) {
                    const int r0l = mi * 16 + q * 4;
#pragma unroll
                    for (int r = 0; r < 4; ++r) {
                        float v = fmaxf(acc[mi][ni][r] + bv, 0.0f);
                        ct[(r0l + r) * 128 + col] = __float2half(v);
                    }
                }
            }
        }
        __syncthreads();
#pragma unroll
        for (int it = 0; it < 4; ++it) {
            const int chunk = it * 256 + t;
            const int row = chunk >> 4;
            const int off = (chunk & 15) * 8;
            *(short8*)&C[(m0 + h * 64 + row) * N + n0 + off] =
                *(const short8*)&ct[row * 128 + off];
        }
    }
}

// ---------------- segment offsets ----------------

__global__ void seg_offsets_kernel(const int* __restrict__ lengths, int* __restrict__ off) {
    if (blockIdx.x == 0 && threadIdx.x == 0) {
        int a = 0;
        off[0] = 0;
        for (int i = 0; i < SEGN; ++i) { a += lengths[i]; off[i + 1] = a; }
    }
}

// ---------------- pooling (4 column-block score partials from gemm256) --------

__global__ __launch_bounds__(256)
void scorepool_kernel(const __half* __restrict__ h4, int slab_beg, int slab_rows,
                      const float* __restrict__ scores_p, const float* __restrict__ b5,
                      const int* __restrict__ segoff,
                      float* __restrict__ pooled, float* __restrict__ denom)
{
    __shared__ float e_sh[FCHUNK];
    const int t = threadIdx.x;
    const int f0 = slab_beg + blockIdx.x * FCHUNK;

    if (t < FCHUNK) {
        const int fl = f0 - slab_beg + t;
        float sc = 0.f;
#pragma unroll
        for (int b = 0; b < 4; ++b) sc += scores_p[(size_t)b * slab_rows + fl];
        sc = fmaxf(sc + b5[0], 0.0f);
        e_sh[t] = __expf(fminf(sc, 80.0f));
    }
    __syncthreads();

    const int c0 = t * 4;
    int lo = 0, hi = SEGN - 1;
    while (lo < hi) {
        int mid = (lo + hi + 1) >> 1;
        if (segoff[mid] <= f0) lo = mid; else hi = mid - 1;
    }
    int s = lo;
    int f = f0;
    const int fend = f0 + FCHUNK;
    const __half* base = h4 + (size_t)(f0 - slab_beg) * HID + c0;
    while (f < fend) {
        int send = segoff[s + 1];
        if (send > fend) send = fend;
        float a0 = 0.f, a1 = 0.f, a2 = 0.f, a3 = 0.f, es = 0.f;
        for (; f < send; ++f, base += HID) {
            float e = e_sh[f - f0];
            const __half2* r2 = (const __half2*)base;
            float2 u = __half22float2(r2[0]);
            float2 v = __half22float2(r2[1]);
            a0 += e * u.x; a1 += e * u.y; a2 += e * v.x; a3 += e * v.y;
            es += e;
        }
        float* p = pooled + (size_t)s * HID + c0;
        atomicAdd(p,     a0);
        atomicAdd(p + 1, a1);
        atomicAdd(p + 2, a2);
        atomicAdd(p + 3, a3);
        if (t == 0) atomicAdd(&denom[s], es);
        ++s;
    }
}

// ---------------- finalize: divide + fp16 ----------------

__global__ __launch_bounds__(256)
void finalize_pool_kernel(const float* __restrict__ pooled, const float* __restrict__ denom,
                          __half* __restrict__ poolh)
{
    int s = blockIdx.x, t = threadIdx.x;
    float inv = 1.0f / denom[s];
    for (int j = t; j < HID; j += 256)
        poolh[(size_t)s * HID + j] = __float2half(pooled[(size_t)s * HID + j] * inv);
}

// ---------------- final head: out = z @ W7 + b7 ----------------

__global__ void final_kernel(const __half* __restrict__ z, const float* __restrict__ W7,
                             const float* __restrict__ b7, float* __restrict__ out) {
    int s = blockIdx.x, t = threadIdx.x;
    float loc[NCLS];
#pragma unroll
    for (int c = 0; c < NCLS; ++c) loc[c] = 0.f;
    for (int k = t; k < HID; k += 256) {
        float zk = __half2float(z[(size_t)s * HID + k]);
        const float* wr = W7 + k * NCLS;
#pragma unroll
        for (int c = 0; c < NCLS; ++c) loc[c] += zk * wr[c];
    }
#pragma unroll
    for (int c = 0; c < NCLS; ++c)
#pragma unroll
        for (int o = 32; o > 0; o >>= 1) loc[c] += __shfl_down(loc[c], o);
    __shared__ float accs[NCLS];
    if (t < NCLS) accs[t] = 0.f;
    __syncthreads();
    if ((t & 63) == 0)
        for (int c = 0; c < NCLS; ++c) atomicAdd(&accs[c], loc[c]);
    __syncthreads();
    if (t < NCLS) out[s * NCLS + t] = accs[t] + b7[t];
}

// ---------------- launch ----------------

extern "C" void kernel_launch(void* const* d_in, const int* in_sizes, int n_in,
                              void* d_out, int out_size, void* d_ws, size_t ws_size,
                              hipStream_t stream) {
    const float* x  = (const float*)d_in[0];
    const float* W1 = (const float*)d_in[1];
    const float* b1 = (const float*)d_in[2];
    const float* W2 = (const float*)d_in[3];
    const float* b2 = (const float*)d_in[4];
    const float* W3 = (const float*)d_in[5];
    const float* b3 = (const float*)d_in[6];
    const float* W4 = (const float*)d_in[7];
    const float* b4 = (const float*)d_in[8];
    const float* W5 = (const float*)d_in[9];
    const float* b5 = (const float*)d_in[10];
    const float* W6 = (const float*)d_in[11];
    const float* b6 = (const float*)d_in[12];
    const float* W7 = (const float*)d_in[13];
    const float* b7 = (const float*)d_in[14];
    const int* lengths = (const int*)d_in[15];
    float* out = (float*)d_out;

    char* ws = (char*)d_ws;
    size_t off = 0;
    auto take = [&](size_t bytes) -> char* {
        char* p = ws + off;
        off = (off + bytes + 255) & ~(size_t)255;
        return p;
    };
    __half* w1t   = (__half*)take((size_t)HID * FPAD * 2);
    __half* w2t   = (__half*)take((size_t)HID * HID * 2);
    __half* w3t   = (__half*)take((size_t)HID * HID * 2);
    __half* w4t   = (__half*)take((size_t)HID * HID * 2);
    __half* w6t   = (__half*)take((size_t)HID * HID * 2);
    int*    segoff = (int*)take((SEGN + 1) * 4);
    float*  pooled = (float*)take((size_t)SEGN * HID * 4);
    float*  denom  = (float*)take(SEGN * 4);
    __half* poolh  = (__half*)take((size_t)SEGN * HID * 2);
    __half* z      = (__half*)take((size_t)SEGN * HID * 2);

    int R = TOTAL;
    while (R > 1024) {
        size_t need = off + (size_t)R * FPAD * 2 + 2 * (size_t)R * HID * 2
                    + (size_t)8 * R * 4 + 4 * 256;
        if (need <= ws_size) break;
        R >>= 1;
    }
    __half* slabX    = (__half*)take((size_t)R * FPAD * 2);
    __half* slabA    = (__half*)take((size_t)R * HID * 2);
    __half* slabB    = (__half*)take((size_t)R * HID * 2);
    float*  scores_p = (float*)take((size_t)8 * R * 4);

    seg_offsets_kernel<<<1, 64, 0, stream>>>(lengths, segoff);
    hipMemsetAsync(pooled, 0, (size_t)SEGN * HID * 4, stream);
    hipMemsetAsync(denom, 0, SEGN * 4, stream);

    conv_wt_kernel<<<(HID * FPAD + 255) / 256, 256, 0, stream>>>(W1, w1t, FEAT, HID, FPAD);
    dim3 gW((HID * HID + 255) / 256, 4);
    conv_w4_kernel<<<gW, 256, 0, stream>>>(W2, W3, W4, W6, w2t, w3t, w4t, w6t);

    const int nBlocksSlab = (R / 128) * (HID / 128);
    const int nBlocks256  = (R / 256) * (HID / 256);
    for (int sb = 0; sb < TOTAL; sb += R) {
        conv_x_slab<<<(R * FPAD + 255) / 256, 256, 0, stream>>>(x, slabX, sb, R);
        gemm_k96<<<nBlocksSlab, 256, 0, stream>>>(slabX, w1t, slabA, b1, R, HID);
        gemm256<<<nBlocks256, 512, 0, stream>>>(slabA, w2t, slabB, b2, R, HID, HID, 1,
                                                nullptr, nullptr);
        gemm256<<<nBlocks256, 512, 0, stream>>>(slabB, w3t, slabA, b3, R, HID, HID, 1,
                                                nullptr, nullptr);
        gemm256<<<nBlocks256, 512, 0, stream>>>(slabA, w4t, slabB, b4, R, HID, HID, 1,
                                                W5, scores_p);
        scorepool_kernel<<<R / FCHUNK, 256, 0, stream>>>(slabB, sb, R, scores_p, b5,
                                                         segoff, pooled, denom);
    }

    finalize_pool_kernel<<<SEGN, 256, 0, stream>>>(pooled, denom, poolh);
    const int nBlocksHead = (SEGN / 128) * (HID / 128);
    gemm_f16<<<nBlocksHead, 256, 0, stream>>>(poolh, w6t, z, b6, SEGN, HID, HID, 1,
                                              nullptr, nullptr);
    final_kernel<<<SEGN, 256, 0, stream>>>(z, W7, b7, out);
}